// Round 6
// baseline (1547.426 us; speedup 1.0000x reference)
//
#include <hip/hip_runtime.h>

#define B_ 2048
#define S_ 128
#define D_ 1024
#define H_ 2048
#define E_ 8
#define NC 10
#define STEPS_ 5

typedef __bf16 bf16_t;
typedef __bf16 bf16x8 __attribute__((ext_vector_type(8)));
typedef __bf16 bf16x4 __attribute__((ext_vector_type(4)));
typedef float f32x4 __attribute__((ext_vector_type(4)));

// ---------------------------------------------------------------------------
// Pool: h[b] = masked mean over S of emb[ids[b,s]]; emits fp32 h + bf16 hi/lo
// planes; inits active list.  (Measured ~155us @ 43% HBM — near gather roofline.)
// ---------------------------------------------------------------------------
__global__ __launch_bounds__(256) void pool_kernel(
    const int* __restrict__ ids, const float* __restrict__ emb,
    float* __restrict__ h, bf16_t* __restrict__ hhi, bf16_t* __restrict__ hlo,
    int* __restrict__ al, int* __restrict__ n_act)
{
    const int b = blockIdx.x;
    const int t = threadIdx.x;
    __shared__ int sid[S_];
    __shared__ float scnt;
    if (t < S_) sid[t] = ids[b * S_ + t];
    __syncthreads();
    if (t == 0) {
        int c = 0;
        for (int j = 0; j < S_; j++) c += (sid[j] != 0) ? 1 : 0;
        scnt = (c > 0) ? (float)c : 1.0f;
    }
    const int d0 = t * 4;
    float ax = 0.f, ay = 0.f, az = 0.f, aw = 0.f;
    for (int j = 0; j < S_; j++) {
        const int id = sid[j];
        if (id != 0) {
            const float4 v = *(const float4*)(emb + (size_t)id * D_ + d0);
            ax += v.x; ay += v.y; az += v.z; aw += v.w;
        }
    }
    __syncthreads();
    const float c = scnt;
    float r[4] = {ax / c, ay / c, az / c, aw / c};
    *(float4*)(h + (size_t)b * D_ + d0) = *(float4*)r;
    bf16x4 hv, lv;
#pragma unroll
    for (int q = 0; q < 4; q++) {
        bf16_t hb = (bf16_t)r[q];
        hv[q] = hb;
        lv[q] = (bf16_t)(r[q] - (float)hb);
    }
    *(bf16x4*)(hhi + (size_t)b * D_ + d0) = hv;
    *(bf16x4*)(hlo + (size_t)b * D_ + d0) = lv;
    if (t == 0) {
        al[b] = b;
        if (b == 0) *n_act = B_;
    }
}

// ---------------------------------------------------------------------------
// Weight convert+transpose: W[e][K][N] fp32 -> hi/lo bf16 planes [e][N][K].
// 32x32 tiles through LDS; grid (K/32, N/32, E).
// ---------------------------------------------------------------------------
__global__ __launch_bounds__(256) void conv_w_kernel(
    const float* __restrict__ W, bf16_t* __restrict__ hi, bf16_t* __restrict__ lo,
    int K, int N)
{
    const int e = blockIdx.z;
    const int k0 = blockIdx.x * 32, n0 = blockIdx.y * 32;
    const float* We = W + (size_t)e * K * N;
    bf16_t* he = hi + (size_t)e * N * K;
    bf16_t* le = lo + (size_t)e * N * K;
    __shared__ float t[32][33];
    const int tid = threadIdx.x;
    const int r = tid >> 3, c4 = (tid & 7) * 4;
    *(float4*)&t[r][c4] = *(const float4*)(We + (size_t)(k0 + r) * N + n0 + c4);
    __syncthreads();
    const int n = r, k4 = c4;
    bf16x4 hv, lv;
#pragma unroll
    for (int q = 0; q < 4; q++) {
        const float x = t[k4 + q][n];
        bf16_t hb = (bf16_t)x;
        hv[q] = hb;
        lv[q] = (bf16_t)(x - (float)hb);
    }
    *(bf16x4*)(he + (size_t)(n0 + n) * K + k0 + k4) = hv;
    *(bf16x4*)(le + (size_t)(n0 + n) * K + k0 + k4) = lv;
}

// ---------------------------------------------------------------------------
// Split-bf16 MFMA gathered GEMM.  C[rows[i]] = sum_k A[rows[i]][k] * W_e[k][n]
// A planes: [*][K] bf16 (k-contig). W planes: [e][N][K] bf16 (k-contig).
// Block 128x128, 4 waves x (64x64), BK=32 (one mfma-K per round).
// XOR-swizzled LDS chunks (16B), single barrier/round.
// [R6] Distance-2 register prefetch: two reg sets in flight; loads for round
// r+2 issued at round r, waited at end of r+1 => ~2 rounds (>800cyc) overlap
// vs ~900cyc HBM latency. Needed because real blocks = 1/CU (no TLP).
// mode 0: store fp32 partial to C + kc*c_es  (split-K, no bias)
// mode 2: x = relu(acc + bias[e][col]); split-store to Chi/Clo bf16 planes
// Grid: (N/128, ceil(maxM/128), E*split_k) -- N-tiles on blockIdx.x so real
// blocks cover all values of (linear_id % 8) => uniform XCD spread.  [R5 fix]
// ---------------------------------------------------------------------------
__global__ __launch_bounds__(256, 2) void gemm_mfma(
    const bf16_t* __restrict__ Ahi, const bf16_t* __restrict__ Alo, int a_rs,
    const bf16_t* __restrict__ Whi, const bf16_t* __restrict__ Wlo, long long w_es,
    int N, int K,
    const float* __restrict__ bias, int bias_es,
    float* __restrict__ C, long long c_es, int c_rs,
    bf16_t* __restrict__ Chi, bf16_t* __restrict__ Clo, int cp_rs,
    const int* __restrict__ rows, int rows_es,
    const int* __restrict__ counts,
    int split_k, int mode)
{
    const int z = blockIdx.z;
    const int e = z / split_k;
    const int kc = z - e * split_k;
    const int cnt = counts[e];
    const int m0 = blockIdx.y * 128;      // m on y
    if (m0 >= cnt) return;
    const int n0 = blockIdx.x * 128;      // n on x (all real)
    const int Kc = K / split_k;
    const int kb0 = kc * Kc;

    __shared__ __align__(16) bf16_t As[2][2][128][32];
    __shared__ __align__(16) bf16_t Bs[2][2][128][32];

    const int tid = threadIdx.x;
    // staging: row = tid>>1, 16 k-elems (2 chunks) at (tid&1)*16
    const int st_r = tid >> 1;
    const int st_c = tid & 1;
    const int sw_w = (st_r & 3) ^ ((st_r >> 2) & 3);
    const int wof0 = ((2 * st_c) ^ sw_w) * 8;
    const int wof1 = ((2 * st_c + 1) ^ sw_w) * 8;

    const int a_i = m0 + st_r;
    const int arow = rows[e * rows_es + (a_i < cnt ? a_i : cnt - 1)];
    const bf16_t* Aph = Ahi + (size_t)arow * a_rs + kb0 + st_c * 16;
    const bf16_t* Apl = Alo + (size_t)arow * a_rs + kb0 + st_c * 16;
    const bf16_t* Bph = Whi + (size_t)e * w_es + (size_t)(n0 + st_r) * K + kb0 + st_c * 16;
    const bf16_t* Bpl = Wlo + (size_t)e * w_es + (size_t)(n0 + st_r) * K + kb0 + st_c * 16;

    const int lane = tid & 63;
    const int w = tid >> 6;
    const int wm = (w >> 1) * 64, wn = (w & 1) * 64;
    const int fr = lane & 15;           // m (A/D-row side) or n (B/D-col side)
    const int cq = lane >> 4;           // k-quad
    const int sw_f = (fr & 3) ^ ((fr >> 2) & 3);
    const int koff = (cq ^ sw_f) * 8;   // swizzled k element offset

    f32x4 acc[4][4];
#pragma unroll
    for (int i = 0; i < 4; i++)
#pragma unroll
        for (int j = 0; j < 4; j++) acc[i][j] = (f32x4){0.f, 0.f, 0.f, 0.f};

    // two in-flight register prefetch sets [R6]
    bf16x8 p0[8], p1[8];

    auto LOADSET = [&](bf16x8* P, int ko) {
        P[0] = *(const bf16x8*)(Aph + ko);
        P[1] = *(const bf16x8*)(Aph + ko + 8);
        P[2] = *(const bf16x8*)(Apl + ko);
        P[3] = *(const bf16x8*)(Apl + ko + 8);
        P[4] = *(const bf16x8*)(Bph + ko);
        P[5] = *(const bf16x8*)(Bph + ko + 8);
        P[6] = *(const bf16x8*)(Bpl + ko);
        P[7] = *(const bf16x8*)(Bpl + ko + 8);
    };
    auto STORESET = [&](int nb, const bf16x8* P) {
        *(bf16x8*)&As[nb][0][st_r][wof0] = P[0];
        *(bf16x8*)&As[nb][0][st_r][wof1] = P[1];
        *(bf16x8*)&As[nb][1][st_r][wof0] = P[2];
        *(bf16x8*)&As[nb][1][st_r][wof1] = P[3];
        *(bf16x8*)&Bs[nb][0][st_r][wof0] = P[4];
        *(bf16x8*)&Bs[nb][0][st_r][wof1] = P[5];
        *(bf16x8*)&Bs[nb][1][st_r][wof0] = P[6];
        *(bf16x8*)&Bs[nb][1][st_r][wof1] = P[7];
    };

    const int nr = Kc / 32;
    LOADSET(p0, 0);
    if (nr > 1) LOADSET(p1, 32);
    STORESET(0, p0);
    __syncthreads();

    int buf = 0;
    for (int r = 0; r < nr; r++) {
        if (r + 2 < nr) LOADSET((r & 1) ? p1 : p0, (r + 2) * 32);

        bf16x8 ah[4], al2[4];
#pragma unroll
        for (int i = 0; i < 4; i++) {
            const int m_loc = wm + i * 16 + fr;
            ah[i]  = *(const bf16x8*)&As[buf][0][m_loc][koff];
            al2[i] = *(const bf16x8*)&As[buf][1][m_loc][koff];
        }
#pragma unroll
        for (int j = 0; j < 4; j++) {
            const int n_loc = wn + j * 16 + fr;
            const bf16x8 bh = *(const bf16x8*)&Bs[buf][0][n_loc][koff];
            const bf16x8 bl = *(const bf16x8*)&Bs[buf][1][n_loc][koff];
#pragma unroll
            for (int i = 0; i < 4; i++) {
                acc[i][j] = __builtin_amdgcn_mfma_f32_16x16x32_bf16(ah[i], bh, acc[i][j], 0, 0, 0);
                acc[i][j] = __builtin_amdgcn_mfma_f32_16x16x32_bf16(ah[i], bl, acc[i][j], 0, 0, 0);
                acc[i][j] = __builtin_amdgcn_mfma_f32_16x16x32_bf16(al2[i], bh, acc[i][j], 0, 0, 0);
            }
        }
        if (r + 1 < nr) {
            const int nb = buf ^ 1;
            STORESET(nb, ((r + 1) & 1) ? p1 : p0);
            __syncthreads();
            buf = nb;
        }
    }

    // epilogue: D mapping col=lane&15, row=(lane>>4)*4+reg  [m89/m91 verified]
    if (mode == 0) {
        float* Cb = C + (size_t)kc * c_es;
#pragma unroll
        for (int i = 0; i < 4; i++) {
#pragma unroll
            for (int rg = 0; rg < 4; rg++) {
                const int mi = m0 + wm + i * 16 + cq * 4 + rg;
                if (mi < cnt) {
                    const int row = rows[e * rows_es + mi];
#pragma unroll
                    for (int j = 0; j < 4; j++) {
                        const int col = n0 + wn + j * 16 + fr;
                        Cb[(size_t)row * c_rs + col] = acc[i][j][rg];
                    }
                }
            }
        }
    } else {
#pragma unroll
        for (int i = 0; i < 4; i++) {
#pragma unroll
            for (int rg = 0; rg < 4; rg++) {
                const int mi = m0 + wm + i * 16 + cq * 4 + rg;
                if (mi < cnt) {
                    const int row = rows[e * rows_es + mi];
#pragma unroll
                    for (int j = 0; j < 4; j++) {
                        const int col = n0 + wn + j * 16 + fr;
                        float x = acc[i][j][rg] + bias[e * bias_es + col];
                        x = fmaxf(x, 0.f);
                        const bf16_t hb = (bf16_t)x;
                        Chi[(size_t)row * cp_rs + col] = hb;
                        Clo[(size_t)row * cp_rs + col] = (bf16_t)(x - (float)hb);
                    }
                }
            }
        }
    }
}

// ---------------------------------------------------------------------------
// Router stage 2: logits = relu(R0+R1 + rb1) @ rW2 + rb2, argmax, terminate or
// bucket. One wave per sample.
// ---------------------------------------------------------------------------
__global__ __launch_bounds__(256) void router2_kernel(
    const float* __restrict__ R0, const float* __restrict__ R1,
    const float* __restrict__ rb1,
    const float* __restrict__ rW2, const float* __restrict__ rb2,
    const float* __restrict__ h,
    float* __restrict__ final_, const int* __restrict__ al,
    const int* __restrict__ n_act, int* __restrict__ counts,
    int* __restrict__ bucket, int* __restrict__ al_next,
    int* __restrict__ n_next, int* __restrict__ act_sel)
{
    const int n = *n_act;
    const int wid = threadIdx.x >> 6;
    const int lane = threadIdx.x & 63;
    const int i = blockIdx.x * 4 + wid;
    if (i >= n) return;
    const int s = al[i];
    const float* x0 = R0 + (size_t)s * D_;
    const float* x1 = R1 + (size_t)s * D_;
    float acc[E_ + 1];
#pragma unroll
    for (int c = 0; c <= E_; c++) acc[c] = 0.f;
    for (int j = 0; j < D_ / 64; j++) {
        const int d = j * 64 + lane;
        const float xv = fmaxf(x0[d] + x1[d] + rb1[d], 0.f);
        const float* wr = rW2 + (size_t)d * (E_ + 1);
#pragma unroll
        for (int c = 0; c <= E_; c++) acc[c] = fmaf(xv, wr[c], acc[c]);
    }
#pragma unroll
    for (int c = 0; c <= E_; c++) {
        float v = acc[c];
        for (int off = 32; off > 0; off >>= 1) v += __shfl_down(v, off, 64);
        acc[c] = v;
    }
    int best = 0;
    if (lane == 0) {
        float bv = acc[0] + rb2[0];
#pragma unroll
        for (int c = 1; c <= E_; c++) {
            const float v = acc[c] + rb2[c];
            if (v > bv) { bv = v; best = c; }   // strict '>' = first-max
        }
    }
    best = __shfl(best, 0, 64);
    if (best == E_) {
        const float* hs = h + (size_t)s * D_;
        float* fs = final_ + (size_t)s * D_;
        for (int d = lane * 4; d < D_; d += 64 * 4)
            *(float4*)(fs + d) = *(const float4*)(hs + d);
    } else if (lane == 0) {
        const int p = atomicAdd(&counts[best], 1);
        bucket[best * B_ + p] = s;
        const int q = atomicAdd(n_next, 1);
        al_next[q] = s;
        act_sel[s] = best;
    }
}

// ---------------------------------------------------------------------------
// LN + residual: h[s] += LN(Y0[s]+Y1[s] + b2_e)*g_e + beta_e; re-emit planes.
// ---------------------------------------------------------------------------
__global__ __launch_bounds__(256) void ln_update_kernel(
    float* __restrict__ h, bf16_t* __restrict__ hhi, bf16_t* __restrict__ hlo,
    const float* __restrict__ Y0, const float* __restrict__ Y1,
    const float* __restrict__ eb2, const float* __restrict__ eg,
    const float* __restrict__ ebeta, const int* __restrict__ al,
    const int* __restrict__ n_ptr, const int* __restrict__ act_sel)
{
    const int n = *n_ptr;
    const int i = blockIdx.x;
    if (i >= n) return;
    const int s = al[i];
    const int e = act_sel[s];
    const int t = threadIdx.x;
    const int lane = t & 63, wid = t >> 6;
    const int d0 = t * 4;

    const float4 y0v = *(const float4*)(Y0 + (size_t)s * D_ + d0);
    const float4 y1v = *(const float4*)(Y1 + (size_t)s * D_ + d0);
    const float4 bv = *(const float4*)(eb2 + (size_t)e * D_ + d0);
    float y0 = y0v.x + y1v.x + bv.x, y1 = y0v.y + y1v.y + bv.y;
    float y2 = y0v.z + y1v.z + bv.z, y3 = y0v.w + y1v.w + bv.w;

    __shared__ float wsum[4];
    __shared__ float stats[2];

    float ssum = y0 + y1 + y2 + y3;
    for (int off = 32; off > 0; off >>= 1) ssum += __shfl_down(ssum, off, 64);
    if (lane == 0) wsum[wid] = ssum;
    __syncthreads();
    if (t == 0) stats[0] = (wsum[0] + wsum[1] + wsum[2] + wsum[3]) * (1.f / D_);
    __syncthreads();
    const float m = stats[0];
    const float e0 = y0 - m, e1 = y1 - m, e2 = y2 - m, e3 = y3 - m;
    float sq = e0 * e0 + e1 * e1 + e2 * e2 + e3 * e3;
    for (int off = 32; off > 0; off >>= 1) sq += __shfl_down(sq, off, 64);
    if (lane == 0) wsum[wid] = sq;
    __syncthreads();
    if (t == 0) {
        const float var = (wsum[0] + wsum[1] + wsum[2] + wsum[3]) * (1.f / D_);
        stats[1] = 1.0f / sqrtf(var + 1e-5f);
    }
    __syncthreads();
    const float rs = stats[1];

    const float4 gv = *(const float4*)(eg + (size_t)e * D_ + d0);
    const float4 btv = *(const float4*)(ebeta + (size_t)e * D_ + d0);
    float* hp = h + (size_t)s * D_ + d0;
    float4 hv = *(const float4*)hp;
    float r[4];
    r[0] = hv.x + e0 * rs * gv.x + btv.x;
    r[1] = hv.y + e1 * rs * gv.y + btv.y;
    r[2] = hv.z + e2 * rs * gv.z + btv.z;
    r[3] = hv.w + e3 * rs * gv.w + btv.w;
    *(float4*)hp = *(float4*)r;
    bf16x4 hq, lq;
#pragma unroll
    for (int q = 0; q < 4; q++) {
        const bf16_t hb = (bf16_t)r[q];
        hq[q] = hb;
        lq[q] = (bf16_t)(r[q] - (float)hb);
    }
    *(bf16x4*)(hhi + (size_t)s * D_ + d0) = hq;
    *(bf16x4*)(hlo + (size_t)s * D_ + d0) = lq;
}

__global__ void reset_kernel(int* __restrict__ counts, int* __restrict__ n_next)
{
    const int t = threadIdx.x;
    if (t < E_) counts[t] = 0;
    if (t == E_) *n_next = 0;
}

__global__ __launch_bounds__(256) void finalize_kernel(
    const int* __restrict__ al, const int* __restrict__ n_ptr,
    const float* __restrict__ h, float* __restrict__ final_)
{
    const int n = *n_ptr;
    const int i = blockIdx.x;
    if (i >= n) return;
    const int s = al[i];
    const int d0 = threadIdx.x * 4;
    *(float4*)(final_ + (size_t)s * D_ + d0) =
        *(const float4*)(h + (size_t)s * D_ + d0);
}

// out[s, 0..9] = final[s] @ oW + ob
__global__ __launch_bounds__(256) void out_head_kernel(
    const float* __restrict__ final_, const float* __restrict__ oW,
    const float* __restrict__ ob, float* __restrict__ out)
{
    const int s = blockIdx.x;
    const int t = threadIdx.x;
    const int lane = t & 63, wid = t >> 6;
    float p[NC];
#pragma unroll
    for (int c = 0; c < NC; c++) p[c] = 0.f;
    for (int d = t; d < D_; d += 256) {
        const float x = final_[(size_t)s * D_ + d];
        const float* wr = oW + (size_t)d * NC;
#pragma unroll
        for (int c = 0; c < NC; c++) p[c] = fmaf(x, wr[c], p[c]);
    }
#pragma unroll
    for (int c = 0; c < NC; c++) {
        float v = p[c];
        for (int off = 32; off > 0; off >>= 1) v += __shfl_down(v, off, 64);
        p[c] = v;
    }
    __shared__ float red[4][NC];
    if (lane == 0) {
#pragma unroll
        for (int c = 0; c < NC; c++) red[wid][c] = p[c];
    }
    __syncthreads();
    if (t < NC)
        out[(size_t)s * NC + t] =
            red[0][t] + red[1][t] + red[2][t] + red[3][t] + ob[t];
}

// ---------------------------------------------------------------------------
extern "C" void kernel_launch(void* const* d_in, const int* in_sizes, int n_in,
                              void* d_out, int out_size, void* d_ws, size_t ws_size,
                              hipStream_t stream)
{
    const int*   ids   = (const int*)d_in[0];
    const float* emb   = (const float*)d_in[1];
    const float* rW1   = (const float*)d_in[2];
    const float* rb1   = (const float*)d_in[3];
    const float* rW2   = (const float*)d_in[4];
    const float* rb2   = (const float*)d_in[5];
    const float* eW1   = (const float*)d_in[6];
    const float* eb1   = (const float*)d_in[7];
    const float* eW2   = (const float*)d_in[8];
    const float* eb2   = (const float*)d_in[9];
    const float* eg    = (const float*)d_in[10];
    const float* ebeta = (const float*)d_in[11];
    const float* oW    = (const float*)d_in[12];
    const float* ob    = (const float*)d_in[13];
    float* out = (float*)d_out;

    // ---- workspace layout ----
    float* h   = (float*)d_ws;                   // B*D
    float* fin = h + (size_t)B_ * D_;            // B*D
    float* Y0  = fin + (size_t)B_ * D_;          // B*D (also router partial R0)
    float* Y1  = Y0 + (size_t)B_ * D_;           // B*D (also router partial R1)
    bf16_t* hhi   = (bf16_t*)(Y1 + (size_t)B_ * D_);   // B*D
    bf16_t* hlo   = hhi + (size_t)B_ * D_;             // B*D
    bf16_t* Zhi   = hlo + (size_t)B_ * D_;             // B*H
    bf16_t* Zlo   = Zhi + (size_t)B_ * H_;             // B*H
    bf16_t* rW1h  = Zlo + (size_t)B_ * H_;             // D*D  ([N][K])
    bf16_t* rW1l  = rW1h + (size_t)D_ * D_;            // D*D
    bf16_t* eW1h  = rW1l + (size_t)D_ * D_;            // E*H*D ([e][N=H][K=D])
    bf16_t* eW1l  = eW1h + (size_t)E_ * H_ * D_;
    bf16_t* eW2h  = eW1l + (size_t)E_ * H_ * D_;       // E*D*H ([e][N=D][K=H])
    bf16_t* eW2l  = eW2h + (size_t)E_ * D_ * H_;
    int* alA     = (int*)(eW2l + (size_t)E_ * D_ * H_);  // B
    int* alB     = alA + B_;                             // B
    int* bucket  = alB + B_;                             // E*B
    int* counts  = bucket + E_ * B_;                     // E
    int* nA      = counts + E_;                          // 1
    int* nB      = nA + 1;                               // 1
    int* act_sel = nB + 1;                               // B

    // ---- one-time (per call) weight plane conversion ----
    conv_w_kernel<<<dim3(D_ / 32, D_ / 32, 1), 256, 0, stream>>>(rW1, rW1h, rW1l, D_, D_);
    conv_w_kernel<<<dim3(D_ / 32, H_ / 32, E_), 256, 0, stream>>>(eW1, eW1h, eW1l, D_, H_);
    conv_w_kernel<<<dim3(H_ / 32, D_ / 32, E_), 256, 0, stream>>>(eW2, eW2h, eW2l, H_, D_);

    pool_kernel<<<B_, 256, 0, stream>>>(ids, emb, h, hhi, hlo, alA, nA);

    int* al_in = alA; int* n_in_p = nA;
    int* al_out = alB; int* n_out_p = nB;

    for (int step = 0; step < STEPS_; step++) {
        reset_kernel<<<1, 64, 0, stream>>>(counts, n_out_p);

        // router hidden partials: R0/R1 = (h @ rW1) split-K 2 (rb1+relu in router2)
        gemm_mfma<<<dim3(D_ / 128, 16, 2), 256, 0, stream>>>(
            hhi, hlo, D_, rW1h, rW1l, 0, D_, D_,
            nullptr, 0,
            Y0, (long long)B_ * D_, D_,
            nullptr, nullptr, 0,
            al_in, 0, n_in_p, 2, 0);

        router2_kernel<<<B_ / 4, 256, 0, stream>>>(
            Y0, Y1, rb1, rW2, rb2, h, fin, al_in, n_in_p,
            counts, bucket, al_out, n_out_p, act_sel);

        // expert L1: Z = relu(h @ eW1_e + eb1_e) -> bf16 planes (fused epilogue)
        gemm_mfma<<<dim3(H_ / 128, 16, E_), 256, 0, stream>>>(
            hhi, hlo, D_, eW1h, eW1l, (long long)H_ * D_, H_, D_,
            eb1, H_,
            nullptr, 0, 0,
            Zhi, Zlo, H_,
            bucket, B_, counts, 1, 2);

        // expert L2 partials: Y0/Y1 = (Z @ eW2_e) split-K 2 (eb2 in LN)
        gemm_mfma<<<dim3(D_ / 128, 16, E_ * 2), 256, 0, stream>>>(
            Zhi, Zlo, H_, eW2h, eW2l, (long long)D_ * H_, D_, H_,
            nullptr, 0,
            Y0, (long long)B_ * D_, D_,
            nullptr, nullptr, 0,
            bucket, B_, counts, 2, 0);

        ln_update_kernel<<<B_, 256, 0, stream>>>(
            h, hhi, hlo, Y0, Y1, eb2, eg, ebeta, al_out, n_out_p, act_sel);

        int* ta = al_in; al_in = al_out; al_out = ta;
        int* tn = n_in_p; n_in_p = n_out_p; n_out_p = tn;
    }

    finalize_kernel<<<B_, 256, 0, stream>>>(al_in, n_in_p, h, fin);
    out_head_kernel<<<B_, 256, 0, stream>>>(fin, oW, ob, out);
}

// Round 7
// 1260.244 us; speedup vs baseline: 1.2279x; 1.2279x over previous
//
#include <hip/hip_runtime.h>

#define B_ 2048
#define S_ 128
#define D_ 1024
#define H_ 2048
#define E_ 8
#define NC 10
#define STEPS_ 5

typedef __bf16 bf16_t;
typedef __bf16 bf16x8 __attribute__((ext_vector_type(8)));
typedef __bf16 bf16x4 __attribute__((ext_vector_type(4)));
typedef float f32x4 __attribute__((ext_vector_type(4)));

// ---------------------------------------------------------------------------
// Pool: h[b] = masked mean over S of emb[ids[b,s]]; emits fp32 h + bf16 hi/lo
// planes; inits active list.  (~155us @ 43% HBM — near gather roofline.)
// ---------------------------------------------------------------------------
__global__ __launch_bounds__(256) void pool_kernel(
    const int* __restrict__ ids, const float* __restrict__ emb,
    float* __restrict__ h, bf16_t* __restrict__ hhi, bf16_t* __restrict__ hlo,
    int* __restrict__ al, int* __restrict__ n_act)
{
    const int b = blockIdx.x;
    const int t = threadIdx.x;
    __shared__ int sid[S_];
    __shared__ float scnt;
    if (t < S_) sid[t] = ids[b * S_ + t];
    __syncthreads();
    if (t == 0) {
        int c = 0;
        for (int j = 0; j < S_; j++) c += (sid[j] != 0) ? 1 : 0;
        scnt = (c > 0) ? (float)c : 1.0f;
    }
    const int d0 = t * 4;
    float ax = 0.f, ay = 0.f, az = 0.f, aw = 0.f;
    for (int j = 0; j < S_; j++) {
        const int id = sid[j];
        if (id != 0) {
            const float4 v = *(const float4*)(emb + (size_t)id * D_ + d0);
            ax += v.x; ay += v.y; az += v.z; aw += v.w;
        }
    }
    __syncthreads();
    const float c = scnt;
    float r[4] = {ax / c, ay / c, az / c, aw / c};
    *(float4*)(h + (size_t)b * D_ + d0) = *(float4*)r;
    bf16x4 hv, lv;
#pragma unroll
    for (int q = 0; q < 4; q++) {
        bf16_t hb = (bf16_t)r[q];
        hv[q] = hb;
        lv[q] = (bf16_t)(r[q] - (float)hb);
    }
    *(bf16x4*)(hhi + (size_t)b * D_ + d0) = hv;
    *(bf16x4*)(hlo + (size_t)b * D_ + d0) = lv;
    if (t == 0) {
        al[b] = b;
        if (b == 0) *n_act = B_;
    }
}

// ---------------------------------------------------------------------------
// Weight convert+transpose: W[e][K][N] fp32 -> hi/lo bf16 planes [e][N][K].
// ---------------------------------------------------------------------------
__global__ __launch_bounds__(256) void conv_w_kernel(
    const float* __restrict__ W, bf16_t* __restrict__ hi, bf16_t* __restrict__ lo,
    int K, int N)
{
    const int e = blockIdx.z;
    const int k0 = blockIdx.x * 32, n0 = blockIdx.y * 32;
    const float* We = W + (size_t)e * K * N;
    bf16_t* he = hi + (size_t)e * N * K;
    bf16_t* le = lo + (size_t)e * N * K;
    __shared__ float t[32][33];
    const int tid = threadIdx.x;
    const int r = tid >> 3, c4 = (tid & 7) * 4;
    *(float4*)&t[r][c4] = *(const float4*)(We + (size_t)(k0 + r) * N + n0 + c4);
    __syncthreads();
    const int n = r, k4 = c4;
    bf16x4 hv, lv;
#pragma unroll
    for (int q = 0; q < 4; q++) {
        const float x = t[k4 + q][n];
        bf16_t hb = (bf16_t)x;
        hv[q] = hb;
        lv[q] = (bf16_t)(x - (float)hb);
    }
    *(bf16x4*)(he + (size_t)(n0 + n) * K + k0 + k4) = hv;
    *(bf16x4*)(le + (size_t)(n0 + n) * K + k0 + k4) = lv;
}

// ---------------------------------------------------------------------------
// Split-bf16 MFMA gathered GEMM, BM=128 x BN=64 tile. [R7]
// 256 thr = 4 waves, wave tile 64x32 (acc 4x2), BK=32, depth-1 reg prefetch,
// XOR-swizzled LDS, 48KB -> up to 3 blocks/CU. Narrow BN doubles real tile
// count (512/dispatch) => ~2 waves/SIMD so ds_read overlaps MFMA across waves.
// mode 0: fp32 partial to C + kc*c_es.   mode 2: relu(acc+bias) -> hi/lo planes.
// do_reset: block (0,0,0) zeroes counts_rst[0..E_-1] and n_rst (consumers of
// these run in later dispatches; safe by stream order).
// Grid: (N/64, ceil(maxM/128), E*split_k); x spans >=8 => uniform XCD spread.
// ---------------------------------------------------------------------------
__global__ __launch_bounds__(256, 3) void gemm_mfma(
    const bf16_t* __restrict__ Ahi, const bf16_t* __restrict__ Alo, int a_rs,
    const bf16_t* __restrict__ Whi, const bf16_t* __restrict__ Wlo, long long w_es,
    int N, int K,
    const float* __restrict__ bias, int bias_es,
    float* __restrict__ C, long long c_es, int c_rs,
    bf16_t* __restrict__ Chi, bf16_t* __restrict__ Clo, int cp_rs,
    const int* __restrict__ rows, int rows_es,
    const int* __restrict__ counts,
    int split_k, int mode,
    int do_reset, int* __restrict__ counts_rst, int* __restrict__ n_rst)
{
    const int tid = threadIdx.x;
    if (do_reset && blockIdx.x == 0 && blockIdx.y == 0 && blockIdx.z == 0) {
        if (tid < E_) counts_rst[tid] = 0;
        if (tid == E_) *n_rst = 0;
    }
    const int z = blockIdx.z;
    const int e = z / split_k;
    const int kc = z - e * split_k;
    const int cnt = counts[e];
    const int m0 = blockIdx.y * 128;
    if (m0 >= cnt) return;
    const int n0 = blockIdx.x * 64;
    const int Kc = K / split_k;
    const int kb0 = kc * Kc;

    __shared__ __align__(16) bf16_t As[2][2][128][32];
    __shared__ __align__(16) bf16_t Bs[2][2][64][32];

    // A staging: 128 rows x 32k, each thread half a row (16 elems) per plane
    const int st_r = tid >> 1;
    const int st_c = tid & 1;
    const int sw_w = (st_r & 3) ^ ((st_r >> 2) & 3);
    const int wof0 = ((2 * st_c) ^ sw_w) * 8;
    const int wof1 = ((2 * st_c + 1) ^ sw_w) * 8;

    const int a_i = m0 + st_r;
    const int arow = rows[e * rows_es + (a_i < cnt ? a_i : cnt - 1)];
    const bf16_t* Aph = Ahi + (size_t)arow * a_rs + kb0 + st_c * 16;
    const bf16_t* Apl = Alo + (size_t)arow * a_rs + kb0 + st_c * 16;

    // B staging: waves 0-1 only (64 rows x 32k, both planes)
    const bool doB = (tid < 128);
    const int b_r = (tid & 127) >> 1;
    const int sw_b = (b_r & 3) ^ ((b_r >> 2) & 3);
    const int bof0 = ((2 * st_c) ^ sw_b) * 8;
    const int bof1 = ((2 * st_c + 1) ^ sw_b) * 8;
    const bf16_t* Bph = Whi + (size_t)e * w_es + (size_t)(n0 + b_r) * K + kb0 + st_c * 16;
    const bf16_t* Bpl = Wlo + (size_t)e * w_es + (size_t)(n0 + b_r) * K + kb0 + st_c * 16;

    const int lane = tid & 63;
    const int w = tid >> 6;
    const int wm = (w >> 1) * 64, wn = (w & 1) * 32;
    const int fr = lane & 15;           // m (A-side) or n (B-side)
    const int cq = lane >> 4;           // k-quad
    const int sw_f = (fr & 3) ^ ((fr >> 2) & 3);
    const int koff = (cq ^ sw_f) * 8;   // swizzled k element offset

    f32x4 acc[4][2];
#pragma unroll
    for (int i = 0; i < 4; i++)
#pragma unroll
        for (int j = 0; j < 2; j++) acc[i][j] = (f32x4){0.f, 0.f, 0.f, 0.f};

    bf16x8 rah0, rah1, ral0, ral1, rbh0, rbh1, rbl0, rbl1;
    rah0 = *(const bf16x8*)(Aph);
    rah1 = *(const bf16x8*)(Aph + 8);
    ral0 = *(const bf16x8*)(Apl);
    ral1 = *(const bf16x8*)(Apl + 8);
    if (doB) {
        rbh0 = *(const bf16x8*)(Bph);
        rbh1 = *(const bf16x8*)(Bph + 8);
        rbl0 = *(const bf16x8*)(Bpl);
        rbl1 = *(const bf16x8*)(Bpl + 8);
    }
    *(bf16x8*)&As[0][0][st_r][wof0] = rah0;
    *(bf16x8*)&As[0][0][st_r][wof1] = rah1;
    *(bf16x8*)&As[0][1][st_r][wof0] = ral0;
    *(bf16x8*)&As[0][1][st_r][wof1] = ral1;
    if (doB) {
        *(bf16x8*)&Bs[0][0][b_r][bof0] = rbh0;
        *(bf16x8*)&Bs[0][0][b_r][bof1] = rbh1;
        *(bf16x8*)&Bs[0][1][b_r][bof0] = rbl0;
        *(bf16x8*)&Bs[0][1][b_r][bof1] = rbl1;
    }
    __syncthreads();

    const int nr = Kc / 32;
    int buf = 0;
    for (int r = 0; r < nr; r++) {
        if (r + 1 < nr) {
            const int ko = (r + 1) * 32;
            rah0 = *(const bf16x8*)(Aph + ko);
            rah1 = *(const bf16x8*)(Aph + ko + 8);
            ral0 = *(const bf16x8*)(Apl + ko);
            ral1 = *(const bf16x8*)(Apl + ko + 8);
            if (doB) {
                rbh0 = *(const bf16x8*)(Bph + ko);
                rbh1 = *(const bf16x8*)(Bph + ko + 8);
                rbl0 = *(const bf16x8*)(Bpl + ko);
                rbl1 = *(const bf16x8*)(Bpl + ko + 8);
            }
        }
        bf16x8 ah[4], al2[4];
#pragma unroll
        for (int i = 0; i < 4; i++) {
            const int m_loc = wm + i * 16 + fr;
            ah[i]  = *(const bf16x8*)&As[buf][0][m_loc][koff];
            al2[i] = *(const bf16x8*)&As[buf][1][m_loc][koff];
        }
#pragma unroll
        for (int j = 0; j < 2; j++) {
            const int n_loc = wn + j * 16 + fr;
            const bf16x8 bh = *(const bf16x8*)&Bs[buf][0][n_loc][koff];
            const bf16x8 bl = *(const bf16x8*)&Bs[buf][1][n_loc][koff];
#pragma unroll
            for (int i = 0; i < 4; i++) {
                acc[i][j] = __builtin_amdgcn_mfma_f32_16x16x32_bf16(ah[i], bh, acc[i][j], 0, 0, 0);
                acc[i][j] = __builtin_amdgcn_mfma_f32_16x16x32_bf16(ah[i], bl, acc[i][j], 0, 0, 0);
                acc[i][j] = __builtin_amdgcn_mfma_f32_16x16x32_bf16(al2[i], bh, acc[i][j], 0, 0, 0);
            }
        }
        if (r + 1 < nr) {
            const int nb = buf ^ 1;
            *(bf16x8*)&As[nb][0][st_r][wof0] = rah0;
            *(bf16x8*)&As[nb][0][st_r][wof1] = rah1;
            *(bf16x8*)&As[nb][1][st_r][wof0] = ral0;
            *(bf16x8*)&As[nb][1][st_r][wof1] = ral1;
            if (doB) {
                *(bf16x8*)&Bs[nb][0][b_r][bof0] = rbh0;
                *(bf16x8*)&Bs[nb][0][b_r][bof1] = rbh1;
                *(bf16x8*)&Bs[nb][1][b_r][bof0] = rbl0;
                *(bf16x8*)&Bs[nb][1][b_r][bof1] = rbl1;
            }
            __syncthreads();
            buf = nb;
        }
    }

    // epilogue: D mapping col=lane&15, row=(lane>>4)*4+reg  [m89/m91 verified]
    if (mode == 0) {
        float* Cb = C + (size_t)kc * c_es;
#pragma unroll
        for (int i = 0; i < 4; i++) {
#pragma unroll
            for (int rg = 0; rg < 4; rg++) {
                const int mi = m0 + wm + i * 16 + cq * 4 + rg;
                if (mi < cnt) {
                    const int row = rows[e * rows_es + mi];
#pragma unroll
                    for (int j = 0; j < 2; j++) {
                        const int col = n0 + wn + j * 16 + fr;
                        Cb[(size_t)row * c_rs + col] = acc[i][j][rg];
                    }
                }
            }
        }
    } else {
#pragma unroll
        for (int i = 0; i < 4; i++) {
#pragma unroll
            for (int rg = 0; rg < 4; rg++) {
                const int mi = m0 + wm + i * 16 + cq * 4 + rg;
                if (mi < cnt) {
                    const int row = rows[e * rows_es + mi];
#pragma unroll
                    for (int j = 0; j < 2; j++) {
                        const int col = n0 + wn + j * 16 + fr;
                        float x = acc[i][j][rg] + bias[e * bias_es + col];
                        x = fmaxf(x, 0.f);
                        const bf16_t hb = (bf16_t)x;
                        Chi[(size_t)row * cp_rs + col] = hb;
                        Clo[(size_t)row * cp_rs + col] = (bf16_t)(x - (float)hb);
                    }
                }
            }
        }
    }
}

// ---------------------------------------------------------------------------
// Router stage 2: logits = relu(R0+R1 + rb1) @ rW2 + rb2, argmax, terminate or
// bucket. One wave per sample.
// ---------------------------------------------------------------------------
__global__ __launch_bounds__(256) void router2_kernel(
    const float* __restrict__ R0, const float* __restrict__ R1,
    const float* __restrict__ rb1,
    const float* __restrict__ rW2, const float* __restrict__ rb2,
    const float* __restrict__ h,
    float* __restrict__ final_, const int* __restrict__ al,
    const int* __restrict__ n_act, int* __restrict__ counts,
    int* __restrict__ bucket, int* __restrict__ al_next,
    int* __restrict__ n_next, int* __restrict__ act_sel)
{
    const int n = *n_act;
    const int wid = threadIdx.x >> 6;
    const int lane = threadIdx.x & 63;
    const int i = blockIdx.x * 4 + wid;
    if (i >= n) return;
    const int s = al[i];
    const float* x0 = R0 + (size_t)s * D_;
    const float* x1 = R1 + (size_t)s * D_;
    float acc[E_ + 1];
#pragma unroll
    for (int c = 0; c <= E_; c++) acc[c] = 0.f;
    for (int j = 0; j < D_ / 64; j++) {
        const int d = j * 64 + lane;
        const float xv = fmaxf(x0[d] + x1[d] + rb1[d], 0.f);
        const float* wr = rW2 + (size_t)d * (E_ + 1);
#pragma unroll
        for (int c = 0; c <= E_; c++) acc[c] = fmaf(xv, wr[c], acc[c]);
    }
#pragma unroll
    for (int c = 0; c <= E_; c++) {
        float v = acc[c];
        for (int off = 32; off > 0; off >>= 1) v += __shfl_down(v, off, 64);
        acc[c] = v;
    }
    int best = 0;
    if (lane == 0) {
        float bv = acc[0] + rb2[0];
#pragma unroll
        for (int c = 1; c <= E_; c++) {
            const float v = acc[c] + rb2[c];
            if (v > bv) { bv = v; best = c; }   // strict '>' = first-max
        }
    }
    best = __shfl(best, 0, 64);
    if (best == E_) {
        const float* hs = h + (size_t)s * D_;
        float* fs = final_ + (size_t)s * D_;
        for (int d = lane * 4; d < D_; d += 64 * 4)
            *(float4*)(fs + d) = *(const float4*)(hs + d);
    } else if (lane == 0) {
        const int p = atomicAdd(&counts[best], 1);
        bucket[best * B_ + p] = s;
        const int q = atomicAdd(n_next, 1);
        al_next[q] = s;
        act_sel[s] = best;
    }
}

// ---------------------------------------------------------------------------
// LN + residual: h[s] += LN(Y0[s]+Y1[s] + b2_e)*g_e + beta_e; re-emit planes.
// ---------------------------------------------------------------------------
__global__ __launch_bounds__(256) void ln_update_kernel(
    float* __restrict__ h, bf16_t* __restrict__ hhi, bf16_t* __restrict__ hlo,
    const float* __restrict__ Y0, const float* __restrict__ Y1,
    const float* __restrict__ eb2, const float* __restrict__ eg,
    const float* __restrict__ ebeta, const int* __restrict__ al,
    const int* __restrict__ n_ptr, const int* __restrict__ act_sel)
{
    const int n = *n_ptr;
    const int i = blockIdx.x;
    if (i >= n) return;
    const int s = al[i];
    const int e = act_sel[s];
    const int t = threadIdx.x;
    const int lane = t & 63, wid = t >> 6;
    const int d0 = t * 4;

    const float4 y0v = *(const float4*)(Y0 + (size_t)s * D_ + d0);
    const float4 y1v = *(const float4*)(Y1 + (size_t)s * D_ + d0);
    const float4 bv = *(const float4*)(eb2 + (size_t)e * D_ + d0);
    float y0 = y0v.x + y1v.x + bv.x, y1 = y0v.y + y1v.y + bv.y;
    float y2 = y0v.z + y1v.z + bv.z, y3 = y0v.w + y1v.w + bv.w;

    __shared__ float wsum[4];
    __shared__ float stats[2];

    float ssum = y0 + y1 + y2 + y3;
    for (int off = 32; off > 0; off >>= 1) ssum += __shfl_down(ssum, off, 64);
    if (lane == 0) wsum[wid] = ssum;
    __syncthreads();
    if (t == 0) stats[0] = (wsum[0] + wsum[1] + wsum[2] + wsum[3]) * (1.f / D_);
    __syncthreads();
    const float m = stats[0];
    const float e0 = y0 - m, e1 = y1 - m, e2 = y2 - m, e3 = y3 - m;
    float sq = e0 * e0 + e1 * e1 + e2 * e2 + e3 * e3;
    for (int off = 32; off > 0; off >>= 1) sq += __shfl_down(sq, off, 64);
    if (lane == 0) wsum[wid] = sq;
    __syncthreads();
    if (t == 0) {
        const float var = (wsum[0] + wsum[1] + wsum[2] + wsum[3]) * (1.f / D_);
        stats[1] = 1.0f / sqrtf(var + 1e-5f);
    }
    __syncthreads();
    const float rs = stats[1];

    const float4 gv = *(const float4*)(eg + (size_t)e * D_ + d0);
    const float4 btv = *(const float4*)(ebeta + (size_t)e * D_ + d0);
    float* hp = h + (size_t)s * D_ + d0;
    float4 hv = *(const float4*)hp;
    float r[4];
    r[0] = hv.x + e0 * rs * gv.x + btv.x;
    r[1] = hv.y + e1 * rs * gv.y + btv.y;
    r[2] = hv.z + e2 * rs * gv.z + btv.z;
    r[3] = hv.w + e3 * rs * gv.w + btv.w;
    *(float4*)hp = *(float4*)r;
    bf16x4 hq, lq;
#pragma unroll
    for (int q = 0; q < 4; q++) {
        const bf16_t hb = (bf16_t)r[q];
        hq[q] = hb;
        lq[q] = (bf16_t)(r[q] - (float)hb);
    }
    *(bf16x4*)(hhi + (size_t)s * D_ + d0) = hq;
    *(bf16x4*)(hlo + (size_t)s * D_ + d0) = lq;
}

__global__ __launch_bounds__(256) void finalize_kernel(
    const int* __restrict__ al, const int* __restrict__ n_ptr,
    const float* __restrict__ h, float* __restrict__ final_)
{
    const int n = *n_ptr;
    const int i = blockIdx.x;
    if (i >= n) return;
    const int s = al[i];
    const int d0 = threadIdx.x * 4;
    *(float4*)(final_ + (size_t)s * D_ + d0) =
        *(const float4*)(h + (size_t)s * D_ + d0);
}

// out[s, 0..9] = final[s] @ oW + ob
__global__ __launch_bounds__(256) void out_head_kernel(
    const float* __restrict__ final_, const float* __restrict__ oW,
    const float* __restrict__ ob, float* __restrict__ out)
{
    const int s = blockIdx.x;
    const int t = threadIdx.x;
    const int lane = t & 63, wid = t >> 6;
    float p[NC];
#pragma unroll
    for (int c = 0; c < NC; c++) p[c] = 0.f;
    for (int d = t; d < D_; d += 256) {
        const float x = final_[(size_t)s * D_ + d];
        const float* wr = oW + (size_t)d * NC;
#pragma unroll
        for (int c = 0; c < NC; c++) p[c] = fmaf(x, wr[c], p[c]);
    }
#pragma unroll
    for (int c = 0; c < NC; c++) {
        float v = p[c];
        for (int off = 32; off > 0; off >>= 1) v += __shfl_down(v, off, 64);
        p[c] = v;
    }
    __shared__ float red[4][NC];
    if (lane == 0) {
#pragma unroll
        for (int c = 0; c < NC; c++) red[wid][c] = p[c];
    }
    __syncthreads();
    if (t < NC)
        out[(size_t)s * NC + t] =
            red[0][t] + red[1][t] + red[2][t] + red[3][t] + ob[t];
}

// ---------------------------------------------------------------------------
extern "C" void kernel_launch(void* const* d_in, const int* in_sizes, int n_in,
                              void* d_out, int out_size, void* d_ws, size_t ws_size,
                              hipStream_t stream)
{
    const int*   ids   = (const int*)d_in[0];
    const float* emb   = (const float*)d_in[1];
    const float* rW1   = (const float*)d_in[2];
    const float* rb1   = (const float*)d_in[3];
    const float* rW2   = (const float*)d_in[4];
    const float* rb2   = (const float*)d_in[5];
    const float* eW1   = (const float*)d_in[6];
    const float* eb1   = (const float*)d_in[7];
    const float* eW2   = (const float*)d_in[8];
    const float* eb2   = (const float*)d_in[9];
    const float* eg    = (const float*)d_in[10];
    const float* ebeta = (const float*)d_in[11];
    const float* oW    = (const float*)d_in[12];
    const float* ob    = (const float*)d_in[13];
    float* out = (float*)d_out;

    // ---- workspace layout ----
    float* h   = (float*)d_ws;                   // B*D
    float* fin = h + (size_t)B_ * D_;            // B*D
    float* Y0  = fin + (size_t)B_ * D_;          // B*D (also router partial R0)
    float* Y1  = Y0 + (size_t)B_ * D_;           // B*D (also router partial R1)
    bf16_t* hhi   = (bf16_t*)(Y1 + (size_t)B_ * D_);   // B*D
    bf16_t* hlo   = hhi + (size_t)B_ * D_;             // B*D
    bf16_t* Zhi   = hlo + (size_t)B_ * D_;             // B*H
    bf16_t* Zlo   = Zhi + (size_t)B_ * H_;             // B*H
    bf16_t* rW1h  = Zlo + (size_t)B_ * H_;             // D*D  ([N][K])
    bf16_t* rW1l  = rW1h + (size_t)D_ * D_;            // D*D
    bf16_t* eW1h  = rW1l + (size_t)D_ * D_;            // E*H*D ([e][N=H][K=D])
    bf16_t* eW1l  = eW1h + (size_t)E_ * H_ * D_;
    bf16_t* eW2h  = eW1l + (size_t)E_ * H_ * D_;       // E*D*H ([e][N=D][K=H])
    bf16_t* eW2l  = eW2h + (size_t)E_ * D_ * H_;
    int* alA     = (int*)(eW2l + (size_t)E_ * D_ * H_);  // B
    int* alB     = alA + B_;                             // B
    int* bucket  = alB + B_;                             // E*B
    int* counts  = bucket + E_ * B_;                     // E
    int* nA      = counts + E_;                          // 1
    int* nB      = nA + 1;                               // 1
    int* act_sel = nB + 1;                               // B

    // ---- one-time (per call) weight plane conversion ----
    conv_w_kernel<<<dim3(D_ / 32, D_ / 32, 1), 256, 0, stream>>>(rW1, rW1h, rW1l, D_, D_);
    conv_w_kernel<<<dim3(D_ / 32, H_ / 32, E_), 256, 0, stream>>>(eW1, eW1h, eW1l, D_, H_);
    conv_w_kernel<<<dim3(H_ / 32, D_ / 32, E_), 256, 0, stream>>>(eW2, eW2h, eW2l, H_, D_);

    pool_kernel<<<B_, 256, 0, stream>>>(ids, emb, h, hhi, hlo, alA, nA);

    int* al_in = alA; int* n_in_p = nA;
    int* al_out = alB; int* n_out_p = nB;

    for (int step = 0; step < STEPS_; step++) {
        // router hidden partials: R0/R1 = (h @ rW1) split-K 2 (rb1+relu in router2)
        // also resets counts/n_out for this step (block 0; consumers run later)
        gemm_mfma<<<dim3(D_ / 64, 16, 2), 256, 0, stream>>>(
            hhi, hlo, D_, rW1h, rW1l, 0, D_, D_,
            nullptr, 0,
            Y0, (long long)B_ * D_, D_,
            nullptr, nullptr, 0,
            al_in, 0, n_in_p, 2, 0,
            1, counts, n_out_p);

        router2_kernel<<<B_ / 4, 256, 0, stream>>>(
            Y0, Y1, rb1, rW2, rb2, h, fin, al_in, n_in_p,
            counts, bucket, al_out, n_out_p, act_sel);

        // expert L1: Z = relu(h @ eW1_e + eb1_e) -> bf16 planes (fused epilogue)
        gemm_mfma<<<dim3(H_ / 64, 16, E_), 256, 0, stream>>>(
            hhi, hlo, D_, eW1h, eW1l, (long long)H_ * D_, H_, D_,
            eb1, H_,
            nullptr, 0, 0,
            Zhi, Zlo, H_,
            bucket, B_, counts, 1, 2,
            0, nullptr, nullptr);

        // expert L2 partials: Y0/Y1 = (Z @ eW2_e) split-K 2 (eb2 in LN)
        gemm_mfma<<<dim3(D_ / 64, 16, E_ * 2), 256, 0, stream>>>(
            Zhi, Zlo, H_, eW2h, eW2l, (long long)D_ * H_, D_, H_,
            nullptr, 0,
            Y0, (long long)B_ * D_, D_,
            nullptr, nullptr, 0,
            bucket, B_, counts, 2, 0,
            0, nullptr, nullptr);

        ln_update_kernel<<<B_, 256, 0, stream>>>(
            h, hhi, hlo, Y0, Y1, eb2, eg, ebeta, al_out, n_out_p, act_sel);

        int* ta = al_in; al_in = al_out; al_out = ta;
        int* tn = n_in_p; n_in_p = n_out_p; n_out_p = tn;
    }

    finalize_kernel<<<B_, 256, 0, stream>>>(al_in, n_in_p, h, fin);
    out_head_kernel<<<B_, 256, 0, stream>>>(fin, oW, ob, out);
}